// Round 3
// baseline (1535.866 us; speedup 1.0000x reference)
//
#include <hip/hip_runtime.h>

#define N_NODES 2048
#define KSEL 50
#define ROWS 8
#define MPT 512

typedef float v2f __attribute__((ext_vector_type(2)));

// ---- order-preserving fp32 <-> uint map (monotone: bigger float => bigger uint)
__device__ __forceinline__ unsigned ford(float f) {
  unsigned b = __float_as_uint(f);
  return b ^ ((b & 0x80000000u) ? 0xFFFFFFFFu : 0x80000000u);
}
__device__ __forceinline__ float funord(unsigned u) {
  unsigned b = (u & 0x80000000u) ? (u ^ 0x80000000u) : ~u;
  return __uint_as_float(b);
}

// 1-sub-counter hist layout: bin b -> word ((b&63)<<2)|(b>>6).
// Scan: lane reads uint4 at [lane*4] = bins {g*64+lane}, g=0..3 (components).
__device__ __forceinline__ int hidx1(unsigned b) {
  return (int)(((b & 63u) << 2) | (b >> 6));
}

// shared single-layer MLP tile: acc[16] = relu(bias + xs^T W), xs transposed layout
__device__ __forceinline__ void mlp_layer(float acc[16], const float* xs,
                                          const float* Ws, const float* bs,
                                          int r, int cg) {
  const float4* Ws4 = (const float4*)Ws;
#pragma unroll
  for (int i = 0; i < 16; ++i) acc[i] = bs[cg * 16 + i];
#pragma unroll 8
  for (int k = 0; k < 64; ++k) {
    float xv = xs[k * 65 + r];
    float4 w0 = Ws4[k * 16 + cg * 4 + 0];
    float4 w1 = Ws4[k * 16 + cg * 4 + 1];
    float4 w2 = Ws4[k * 16 + cg * 4 + 2];
    float4 w3 = Ws4[k * 16 + cg * 4 + 3];
    acc[0]  += xv * w0.x; acc[1]  += xv * w0.y; acc[2]  += xv * w0.z; acc[3]  += xv * w0.w;
    acc[4]  += xv * w1.x; acc[5]  += xv * w1.y; acc[6]  += xv * w1.z; acc[7]  += xv * w1.w;
    acc[8]  += xv * w2.x; acc[9]  += xv * w2.y; acc[10] += xv * w2.z; acc[11] += xv * w2.w;
    acc[12] += xv * w3.x; acc[13] += xv * w3.y; acc[14] += xv * w3.z; acc[15] += xv * w3.w;
  }
#pragma unroll
  for (int i = 0; i < 16; ++i) acc[i] = fmaxf(acc[i], 0.f);
}

// Fused embedding: h1=relu(x@w0+b0); h2=relu(h1@w1+b1) -> A, AT; msg0=relu(h2@wm+bm) -> M
__global__ __launch_bounds__(256) void emb3_kernel(
    const float* __restrict__ x,
    const float* __restrict__ ew0, const float* __restrict__ eb0,
    const float* __restrict__ ew1, const float* __restrict__ eb1,
    const float* __restrict__ wmm, const float* __restrict__ bmm,
    float* __restrict__ outA, float* __restrict__ outAT, float* __restrict__ outM)
{
  const int tid = threadIdx.x;
  const int r = tid & 63, cg = tid >> 6;
  const size_t rowbase = (size_t)blockIdx.x * 64;
  __shared__ float xs[64 * 65];
  __shared__ float Ws[64 * 64];
  __shared__ float bs[64];
  float acc[16];

#pragma unroll
  for (int i = 0; i < 16; ++i) {
    int idx = tid + 256 * i;
    xs[(idx & 63) * 65 + (idx >> 6)] = x[rowbase * 64 + idx];
    Ws[idx] = ew0[idx];
  }
  if (tid < 64) bs[tid] = eb0[tid];
  __syncthreads();
  mlp_layer(acc, xs, Ws, bs, r, cg);             // h1
  __syncthreads();
#pragma unroll
  for (int i = 0; i < 16; ++i) {
    xs[(cg * 16 + i) * 65 + r] = acc[i];
    Ws[tid + 256 * i] = ew1[tid + 256 * i];
  }
  if (tid < 64) bs[tid] = eb1[tid];
  __syncthreads();
  mlp_layer(acc, xs, Ws, bs, r, cg);             // h2
  {
    float4* o4 = (float4*)(outA + (rowbase + r) * 64 + cg * 16);
#pragma unroll
    for (int q = 0; q < 4; ++q)
      o4[q] = make_float4(acc[q*4+0], acc[q*4+1], acc[q*4+2], acc[q*4+3]);
  }
  __syncthreads();
#pragma unroll
  for (int i = 0; i < 16; ++i) {
    xs[(cg * 16 + i) * 65 + r] = acc[i];
    Ws[tid + 256 * i] = wmm[tid + 256 * i];
  }
  if (tid < 64) bs[tid] = bmm[tid];
  __syncthreads();
  {   // flush AT (h2 transposed, feature-major)
    const size_t bb = rowbase >> 11;
    const int nbase = (int)(rowbase & 2047);
    const int c = tid >> 2, seg = tid & 3;
    float* oT = outAT + bb * 64 * N_NODES + (size_t)c * N_NODES + nbase + seg * 16;
#pragma unroll
    for (int q = 0; q < 4; ++q)
      ((float4*)oT)[q] = make_float4(xs[c*65+seg*16+q*4+0], xs[c*65+seg*16+q*4+1],
                                     xs[c*65+seg*16+q*4+2], xs[c*65+seg*16+q*4+3]);
  }
  mlp_layer(acc, xs, Ws, bs, r, cg);             // msg0
  {
    float4* o4 = (float4*)(outM + (rowbase + r) * 64 + cg * 16);
#pragma unroll
    for (int q = 0; q < 4; ++q)
      o4[q] = make_float4(acc[q*4+0], acc[q*4+1], acc[q*4+2], acc[q*4+3]);
  }
}

// plain single-layer linrelu (msg1)
__global__ __launch_bounds__(256) void linrelu_kernel(
    const float* __restrict__ in, const float* __restrict__ W,
    const float* __restrict__ bias, float* __restrict__ out)
{
  const int tid = threadIdx.x;
  const int r = tid & 63, cg = tid >> 6;
  const size_t rowbase = (size_t)blockIdx.x * 64;
  __shared__ float xs[64 * 65];
  __shared__ float Ws[64 * 64];
  __shared__ float bs[64];
  float acc[16];
#pragma unroll
  for (int i = 0; i < 16; ++i) {
    int idx = tid + 256 * i;
    xs[(idx & 63) * 65 + (idx >> 6)] = in[rowbase * 64 + idx];
    Ws[idx] = W[idx];
  }
  if (tid < 64) bs[tid] = bias[tid];
  __syncthreads();
  mlp_layer(acc, xs, Ws, bs, r, cg);
  float4* o4 = (float4*)(out + (rowbase + r) * 64 + cg * 16);
#pragma unroll
  for (int q = 0; q < 4; ++q)
    o4[q] = make_float4(acc[q*4+0], acc[q*4+1], acc[q*4+2], acc[q*4+3]);
}

// R18: same register-resident select as R17, plus:
//  (1) __launch_bounds__(512,8): allow 4 blocks/CU co-resident -> phase
//      diversity hides select-phase latency under other blocks' FMA issue
//      (R17 showed 54% occupancy with all waves barrier-locked in-phase).
//  (2) 2-way sub-counter histograms (word = hidx1(bin)*2 | (tid&1)): halves
//      same-address LDS-atomic serialization (7.5M conflict-cycles in R17).
//  (3) doneCnt early-exit on the refinement loop (rows usually resolve in
//      2-3 of the 4 fixed iterations -> skip dead sweeps+barriers).
template <bool FINAL>
__global__ __launch_bounds__(MPT, 8) void mp_kernel(
    const float* __restrict__ h, const float* __restrict__ hT,
    const float* __restrict__ msg,
    const float* __restrict__ wu, const float* __restrict__ bu,
    float* __restrict__ outp, float* __restrict__ outT)
{
  const int tid = threadIdx.x;
  const int lane = tid & 63;
  const int w64 = tid >> 6;               // 8 waves <-> 8 rows
  const int bid = blockIdx.x;
  const int b = bid & 7;                  // round-robin blockIdx->XCD: 1 batch/XCD
  const int n0 = (bid >> 3) * ROWS;

  __shared__ unsigned hist[ROWS][512];    // 16 KB: 2 sub-counters/bin; otF overlay
  __shared__ int      seli[ROWS][52];
  __shared__ float    selv[ROWS][52];
  __shared__ int      eqR [ROWS][56];
  __shared__ float    hrL [ROWS * 64];
  __shared__ float    aggB[ROWS][64];
  __shared__ unsigned rowL[ROWS], rowM[ROWS];
  __shared__ unsigned stateA[ROWS], pvA[ROWS], rowLv[ROWS], probeV[ROWS];
  __shared__ unsigned wcnt[ROWS][ROWS];   // [wave][row]: winners | (ties<<16)
  __shared__ int      doneCnt;

  const float* hb  = h  + (size_t)b * N_NODES * 64;
  const float* hTb = hT + (size_t)b * 64 * N_NODES;
  const float* colp = hTb + 4 * tid;      // this thread's 4 columns
  const int sub = tid & 1;                // histogram sub-counter

  // prefetch ring depth 4 (issued before anything else)
  float4 pf[4];
#pragma unroll
  for (int i = 0; i < 4; ++i)
    pf[i] = *(const float4*)(colp + (size_t)i * 2048);

  if (!FINAL) hrL[tid] = hb[(size_t)n0 * 64 + tid];    // ROWS*64 == 512
  for (int i = tid; i < ROWS * 512; i += MPT) (&hist[0][0])[i] = 0;
  if (tid < ROWS) { rowL[tid] = 0; rowM[tid] = 0; }
  if (tid == 0) doneCnt = 0;

  // ---- FMA phase: acc2[r*2+q]: row r, column pair q (4 cols/thread)
  v2f acc2[16];
#pragma unroll
  for (int i = 0; i < 16; ++i) { acc2[i][0] = 0.f; acc2[i][1] = 0.f; }

  const float* hrow = hb + (size_t)n0 * 64;            // block-uniform -> SGPR
  float4 a_cur[ROWS], a_nxt[ROWS];
#pragma unroll
  for (int r = 0; r < ROWS; ++r)
    a_cur[r] = *(const float4*)(hrow + r * 64);
  for (int k4 = 0; k4 < 16; ++k4) {
    if (k4 + 1 < 16) {                                 // prefetch next k4's rows
#pragma unroll
      for (int r = 0; r < ROWS; ++r)
        a_nxt[r] = *(const float4*)(hrow + r * 64 + (k4 + 1) * 4);
    }
#pragma unroll
    for (int kk = 0; kk < 4; ++kk) {
      const int k = k4 * 4 + kk;
      float4 c = pf[kk];                               // ring: kk == k&3
      if (k + 4 < 64)
        pf[kk] = *(const float4*)(colp + (size_t)(k + 4) * 2048);
      v2f c0 = {c.x, c.y}, c1 = {c.z, c.w};
#pragma unroll
      for (int r = 0; r < ROWS; ++r) {
        const float ar = ((const float*)&a_cur[r])[kk];
        v2f as = {ar, ar};
        acc2[r*2+0] = __builtin_elementwise_fma(as, c0, acc2[r*2+0]);
        acc2[r*2+1] = __builtin_elementwise_fma(as, c1, acc2[r*2+1]);
      }
    }
#pragma unroll
    for (int r = 0; r < ROWS; ++r) a_cur[r] = a_nxt[r];
  }

  // ---- ford in place; values stay in registers for the whole select
  unsigned uv[32];
#pragma unroll
  for (int r = 0; r < ROWS; ++r) {
    uv[r*4+0] = ford(acc2[r*2+0][0]); uv[r*4+1] = ford(acc2[r*2+0][1]);
    uv[r*4+2] = ford(acc2[r*2+1][0]); uv[r*4+3] = ford(acc2[r*2+1][1]);
  }

  __syncthreads();                        // barrier 1: LDS init visible

  // ---- per-row L (max of wave-mins of lane-maxes) and M (row max)
#pragma unroll
  for (int r = 0; r < ROWS; ++r) {
    unsigned m1 = uv[r*4+0] > uv[r*4+1] ? uv[r*4+0] : uv[r*4+1];
    unsigned m2 = uv[r*4+2] > uv[r*4+3] ? uv[r*4+2] : uv[r*4+3];
    unsigned lm = m1 > m2 ? m1 : m2;
    unsigned mn = lm, mx = lm;
#pragma unroll
    for (int off = 32; off >= 1; off >>= 1) {
      unsigned o1 = (unsigned)__shfl_xor((int)mn, off, 64);
      unsigned o2 = (unsigned)__shfl_xor((int)mx, off, 64);
      mn = mn < o1 ? mn : o1;
      mx = mx > o2 ? mx : o2;
    }
    if (lane == 0) { atomicMax(&rowL[r], mn); atomicMax(&rowM[r], mx); }
  }
  __syncthreads();                        // barrier 2: rowL/rowM final

  // ---- per-row state init (mode: 0=HIST 1=PROBE 2=DONE; state=(Kc<<16)|(mode<<8)|s2)
  if (tid < ROWS) {
    unsigned L = rowL[tid], M = rowM[tid];
    unsigned st, pv;
    if (L == M) { st = (2u << 8); pv = M; atomicAdd(&doneCnt, 1); }              // >=64 copies of max
    else if ((L >> 24) == (M >> 24)) { st = (50u << 16) | 24u;    pv = M >> 24; } // skip byte3 pass
    else                         { st = (50u << 16) | 32u;        pv = 0; }
    stateA[tid] = st; pvA[tid] = pv; rowLv[tid] = L;
  }
  __syncthreads();                        // barrier 3: states visible

  // ---- up to 4 refinement iterations (worst case bytes 3,2,1,0; probe folds in)
  for (int it = 0; it < 4; ++it) {
    if (doneCnt == ROWS) break;           // block-uniform (read post-barrier)
    // test phase: every thread tests its 32 register values
#pragma unroll
    for (int r = 0; r < ROWS; ++r) {
      unsigned st = stateA[r];
      unsigned mode = (st >> 8) & 3u;
      if (mode == 2u) continue;           // block-uniform per row
      unsigned s2 = st & 255u;
      unsigned pv = pvA[r];
      unsigned Lr = rowLv[r];
      if (mode == 0u) {                   // HIST
        unsigned shn = s2 - 8u;
#pragma unroll
        for (int j = 0; j < 4; ++j) {
          unsigned v = uv[r*4+j];
          bool ok = (v >= Lr) && (s2 >= 32u || (v >> s2) == pv);
          if (ok) atomicAdd(&hist[r][(hidx1((v >> shn) & 255u) << 1) | sub], 1u);
        }
      } else {                            // PROBE: unique candidate in range
        unsigned lo = pv << s2;
        unsigned hi = lo | ((1u << s2) - 1u);
        unsigned lo2 = lo > Lr ? lo : Lr;
#pragma unroll
        for (int j = 0; j < 4; ++j) {
          unsigned v = uv[r*4+j];
          if (v >= lo2 && v <= hi) probeV[r] = v;   // exactly one matches (cnt==1)
        }
      }
    }
    __syncthreads();
    // scan phase: wave w64 scans row w64
    {
      unsigned st = stateA[w64];
      unsigned mode = (st >> 8) & 3u;
      if (mode == 0u) {
        unsigned s2 = st & 255u;
        unsigned Kc = st >> 16;
        unsigned pv = pvA[w64];
        uint4 q0 = *(const uint4*)&hist[w64][lane * 8];
        uint4 q1 = *(const uint4*)&hist[w64][lane * 8 + 4];
        *(uint4*)&hist[w64][lane * 8]     = make_uint4(0, 0, 0, 0);
        *(uint4*)&hist[w64][lane * 8 + 4] = make_uint4(0, 0, 0, 0);
        unsigned c0 = q0.x + q0.y, c1 = q0.z + q0.w;
        unsigned c2 = q1.x + q1.y, c3 = q1.z + q1.w;
        unsigned t0s = c0, t1s = c1, t2s = c2, t3s = c3;   // suffix over lanes
#pragma unroll
        for (int off = 1; off < 64; off <<= 1) {
          unsigned u0=__shfl_down((int)t0s,off,64), u1=__shfl_down((int)t1s,off,64);
          unsigned u2=__shfl_down((int)t2s,off,64), u3=__shfl_down((int)t3s,off,64);
          if (lane + off < 64) { t0s+=u0; t1s+=u1; t2s+=u2; t3s+=u3; }
        }
        unsigned T1=(unsigned)__shfl((int)t1s,0,64);
        unsigned T2=(unsigned)__shfl((int)t2s,0,64);
        unsigned T3=(unsigned)__shfl((int)t3s,0,64);
        unsigned cA4[4] = {c0, c1, c2, c3};
        unsigned AA[4] = {t0s - c0 + T1 + T2 + T3, t1s - c1 + T2 + T3,
                          t2s - c2 + T3,           t3s - c3};
        int fg = -1;
#pragma unroll
        for (int g = 0; g < 4; ++g)
          if (AA[g] < Kc && Kc <= AA[g] + cA4[g]) fg = g;
        unsigned long long mk = __ballot(fg >= 0);
        int src = __ffsll(mk) - 1;        // exactly one lane fires
        unsigned bin = 0, nKc = 0, cnt = 0;
        if (fg >= 0) {
          bin = (unsigned)(fg * 64 + lane);
          nKc = Kc - AA[fg];
          cnt = cA4[fg];
        }
        bin = (unsigned)__shfl((int)bin, src, 64);
        nKc = (unsigned)__shfl((int)nKc, src, 64);
        cnt = (unsigned)__shfl((int)cnt, src, 64);
        pv = (pv << 8) | bin;
        Kc = nKc;
        s2 -= 8;
        unsigned nmode = (s2 == 0) ? 2u : (cnt == 1 ? 1u : 0u);
        if (lane == 0) {
          stateA[w64] = (Kc << 16) | (nmode << 8) | s2; pvA[w64] = pv;
          if (nmode == 2u) atomicAdd(&doneCnt, 1);
        }
      } else if (mode == 1u) {
        if (lane == 0) {
          pvA[w64] = probeV[w64]; stateA[w64] = (2u << 8);
          atomicAdd(&doneCnt, 1);
        }
      }
    }
    __syncthreads();
  }

  // ---- extraction: all rows DONE, Tv[r] in pvA[r]; deterministic ordered compaction
  int pkPre[ROWS];
#pragma unroll
  for (int r = 0; r < ROWS; ++r) {
    unsigned Tv = pvA[r];
    int g = 0, e = 0;
#pragma unroll
    for (int j = 0; j < 4; ++j) {
      unsigned v = uv[r*4+j];
      g += (v > Tv); e += (v == Tv);
    }
    int pk = g | (e << 16);
    int inc = pk;
#pragma unroll
    for (int off = 1; off < 64; off <<= 1) {
      int t = __shfl_up(inc, off, 64);
      if (lane >= off) inc += t;
    }
    if (lane == 63) wcnt[w64][r] = (unsigned)inc;
    pkPre[r] = inc - pk;                   // exclusive within-wave prefix
  }
  if constexpr (FINAL) {
    // masked dense rows straight from registers (ties fixed up after resolve)
#pragma unroll
    for (int r = 0; r < ROWS; ++r) {
      unsigned Tv = pvA[r];
      float4 w; float* wf = (float*)&w;
#pragma unroll
      for (int j = 0; j < 4; ++j) {
        unsigned v = uv[r*4+j];
        wf[j] = (v > Tv) ? funord(v) : 0.f;
      }
      *(float4*)(outp + ((size_t)b * N_NODES + n0 + r) * N_NODES + 4 * tid) = w;
    }
  }
  __syncthreads();                         // wcnt visible

#pragma unroll
  for (int r = 0; r < ROWS; ++r) {
    unsigned Tv = pvA[r];
    int base = 0;
#pragma unroll
    for (int w2 = 0; w2 < ROWS; ++w2)
      if (w2 < w64) base += (int)wcnt[w2][r];
    int tot = base + pkPre[r];
    int gb = tot & 0xFFFF, eb = tot >> 16;
#pragma unroll
    for (int j = 0; j < 4; ++j) {
      unsigned v = uv[r*4+j];
      int m = 4 * tid + j;
      if (!FINAL && v > Tv) { seli[r][gb] = m; selv[r][gb] = funord(v); ++gb; }
      if (v == Tv) { if (eb < 56) eqR[r][eb] = m; ++eb; }
    }
  }
  __syncthreads();                         // seli/selv/eqR visible

  // ---- per-wave tail: wave w64 owns row rw
  const int rw = w64;
  const unsigned Tv = pvA[rw];
  int gW, eTot;
  {
    int t = 0;
#pragma unroll
    for (int w2 = 0; w2 < ROWS; ++w2) t += (int)wcnt[w2][rw];
    gW = t & 0xFFFF; eTot = t >> 16;
  }
  const int eW = eTot < 56 ? eTot : 56;
  const int needW = KSEL - gW;
  const float Tf = funord(Tv);
  float* ob = FINAL ? (outp + ((size_t)b * N_NODES + n0 + rw) * N_NODES) : nullptr;

  {  // tie-resolve, wave-parallel: `need` smallest indices among equals
    int myi = (lane < eW) ? eqR[rw][lane] : 0x7FFFFFFF;
    for (int t = 0; t < needW; ++t) {
      int mn = myi;
#pragma unroll
      for (int off = 32; off >= 1; off >>= 1) {
        int o = __shfl_xor(mn, off, 64);
        mn = mn < o ? mn : o;
      }
      if (mn == 0x7FFFFFFF) break;
      if (myi == mn) {
        if (!FINAL) { seli[rw][gW + t] = mn; selv[rw][gW + t] = Tf; }
        else eqR[rw][t] = mn;              // reuse as fixup list
        myi = 0x7FFFFFFF;
      }
    }
  }

  if constexpr (FINAL) {
    if (lane < needW) ob[eqR[rw][lane]] = Tf;          // tie fixups
  } else {
    // aggregation: batched gather, 10 independent L2 loads in flight
    {
      const float* msgb = msg + (size_t)b * N_NODES * 64;
      float a0 = 0.f, a1 = 0.f;
#pragma unroll
      for (int i0 = 0; i0 < KSEL; i0 += 10) {
        int mi[10]; float vv[10], mv[10];
#pragma unroll
        for (int j = 0; j < 10; ++j) {
          mi[j] = seli[rw][i0 + j];        // wave-uniform LDS broadcast
          vv[j] = selv[rw][i0 + j];
        }
#pragma unroll
        for (int j = 0; j < 10; ++j)
          mv[j] = msgb[(size_t)mi[j] * 64 + lane];
#pragma unroll
        for (int j = 0; j < 10; ++j) {
          if (j & 1) a1 += vv[j] * mv[j];
          else       a0 += vv[j] * mv[j];
        }
      }
      aggB[rw][lane] = a0 + a1;
    }
    // update MLP: h2[rw][lane]; dual chains break the serial FMA dependency
    float s0 = bu[lane], s1 = 0.f;
#pragma unroll 8
    for (int jj = 0; jj < 64; jj += 2) {
      s0 += hrL[rw * 64 + jj]     * wu[jj * 64 + lane];
      s1 += hrL[rw * 64 + jj + 1] * wu[(jj + 1) * 64 + lane];
    }
#pragma unroll 8
    for (int jj = 0; jj < 64; jj += 2) {
      s0 += aggB[rw][jj]     * wu[(64 + jj) * 64 + lane];
      s1 += aggB[rw][jj + 1] * wu[(64 + jj + 1) * 64 + lane];
    }
    float s = fmaxf(s0 + s1, 0.f);
    outp[((size_t)b * N_NODES + n0 + rw) * 64 + lane] = s;
    __syncthreads();                       // all waves past selection
    float* otF = (float*)&hist[0][0];      // transpose staging overlay (hist dead)
    otF[lane * 9 + rw] = s;                // stride 9: conflict-free
    __syncthreads();
    {                                      // flush h2T: 64 feats x 8 rows
      int f = tid >> 3, rr = tid & 7;
      outT[(size_t)b * 64 * N_NODES + (size_t)f * N_NODES + n0 + rr] = otF[f * 9 + rr];
    }
  }
}

extern "C" void kernel_launch(void* const* d_in, const int* in_sizes, int n_in,
                              void* d_out, int out_size, void* d_ws, size_t ws_size,
                              hipStream_t stream)
{
  (void)in_sizes; (void)n_in; (void)out_size; (void)ws_size;
  const float* x   = (const float*)d_in[0];
  const float* ew0 = (const float*)d_in[1];
  const float* eb0 = (const float*)d_in[2];
  const float* ew1 = (const float*)d_in[3];
  const float* eb1 = (const float*)d_in[4];
  const float* w0m = (const float*)d_in[5];
  const float* b0m = (const float*)d_in[6];
  const float* w0u = (const float*)d_in[7];
  const float* b0u = (const float*)d_in[8];
  const float* w1m = (const float*)d_in[9];
  const float* b1m = (const float*)d_in[10];
  const float* w1u = (const float*)d_in[11];
  const float* b1u = (const float*)d_in[12];
  float* out = (float*)d_out;
  float* ws = (float*)d_ws;

  const size_t BUF = (size_t)8 * N_NODES * 64;  // 4 MB each, 20 MB total ws
  float* A   = ws;
  float* AT  = ws + 1 * BUF;
  float* Bf  = ws + 2 * BUF;
  float* BfT = ws + 3 * BUF;
  float* C   = ws + 4 * BUF;

  const int NBLK = 8 * (N_NODES / ROWS);        // 2048

  // fused embedding (2 layers) + msg0
  emb3_kernel<<<256, 256, 0, stream>>>(x, ew0, eb0, ew1, eb1, w0m, b0m, A, AT, C);

  // MP layer 0 (consumes msg0=C, produces Bf/BfT)
  mp_kernel<false><<<NBLK, MPT, 0, stream>>>(A, AT, C, w0u, b0u, Bf, BfT);

  // msg1
  linrelu_kernel<<<256, 256, 0, stream>>>(Bf, w1m, b1m, C);

  // MP layer 1
  mp_kernel<false><<<NBLK, MPT, 0, stream>>>(Bf, BfT, C, w1u, b1u, A, AT);

  // final dense top-k adjacency
  mp_kernel<true><<<NBLK, MPT, 0, stream>>>(A, AT, nullptr, nullptr, nullptr, out, nullptr);
}

// Round 5
// 531.259 us; speedup vs baseline: 2.8910x; 2.8910x over previous
//
#include <hip/hip_runtime.h>

#define N_NODES 2048
#define KSEL 50
#define ROWS 4

typedef float v2f __attribute__((ext_vector_type(2)));

// ---- order-preserving fp32 <-> uint map (monotone: bigger float => bigger uint)
__device__ __forceinline__ unsigned ford(float f) {
  unsigned b = __float_as_uint(f);
  return b ^ ((b & 0x80000000u) ? 0xFFFFFFFFu : 0x80000000u);
}
__device__ __forceinline__ float funord(unsigned u) {
  unsigned b = (u & 0x80000000u) ? (u ^ 0x80000000u) : ~u;
  return __uint_as_float(b);
}

// 1-sub-counter hist layout: bin b -> word ((b&63)<<2)|(b>>6).
// Scan: lane reads uint4 at [lane*4] = bins {g*64+lane}, g=0..3 (components).
__device__ __forceinline__ int hidx1(unsigned b) {
  return (int)(((b & 63u) << 2) | (b >> 6));
}

// shared single-layer MLP tile: acc[16] = relu(bias + xs^T W), xs transposed layout
__device__ __forceinline__ void mlp_layer(float acc[16], const float* xs,
                                          const float* Ws, const float* bs,
                                          int r, int cg) {
  const float4* Ws4 = (const float4*)Ws;
#pragma unroll
  for (int i = 0; i < 16; ++i) acc[i] = bs[cg * 16 + i];
#pragma unroll 8
  for (int k = 0; k < 64; ++k) {
    float xv = xs[k * 65 + r];
    float4 w0 = Ws4[k * 16 + cg * 4 + 0];
    float4 w1 = Ws4[k * 16 + cg * 4 + 1];
    float4 w2 = Ws4[k * 16 + cg * 4 + 2];
    float4 w3 = Ws4[k * 16 + cg * 4 + 3];
    acc[0]  += xv * w0.x; acc[1]  += xv * w0.y; acc[2]  += xv * w0.z; acc[3]  += xv * w0.w;
    acc[4]  += xv * w1.x; acc[5]  += xv * w1.y; acc[6]  += xv * w1.z; acc[7]  += xv * w1.w;
    acc[8]  += xv * w2.x; acc[9]  += xv * w2.y; acc[10] += xv * w2.z; acc[11] += xv * w2.w;
    acc[12] += xv * w3.x; acc[13] += xv * w3.y; acc[14] += xv * w3.z; acc[15] += xv * w3.w;
  }
#pragma unroll
  for (int i = 0; i < 16; ++i) acc[i] = fmaxf(acc[i], 0.f);
}

// Fused embedding: h1=relu(x@w0+b0); h2=relu(h1@w1+b1) -> A, AT; msg0=relu(h2@wm+bm) -> M
__global__ __launch_bounds__(256) void emb3_kernel(
    const float* __restrict__ x,
    const float* __restrict__ ew0, const float* __restrict__ eb0,
    const float* __restrict__ ew1, const float* __restrict__ eb1,
    const float* __restrict__ wmm, const float* __restrict__ bmm,
    float* __restrict__ outA, float* __restrict__ outAT, float* __restrict__ outM)
{
  const int tid = threadIdx.x;
  const int r = tid & 63, cg = tid >> 6;
  const size_t rowbase = (size_t)blockIdx.x * 64;
  __shared__ float xs[64 * 65];
  __shared__ float Ws[64 * 64];
  __shared__ float bs[64];
  float acc[16];

#pragma unroll
  for (int i = 0; i < 16; ++i) {
    int idx = tid + 256 * i;
    xs[(idx & 63) * 65 + (idx >> 6)] = x[rowbase * 64 + idx];
    Ws[idx] = ew0[idx];
  }
  if (tid < 64) bs[tid] = eb0[tid];
  __syncthreads();
  mlp_layer(acc, xs, Ws, bs, r, cg);             // h1
  __syncthreads();
#pragma unroll
  for (int i = 0; i < 16; ++i) {
    xs[(cg * 16 + i) * 65 + r] = acc[i];
    Ws[tid + 256 * i] = ew1[tid + 256 * i];
  }
  if (tid < 64) bs[tid] = eb1[tid];
  __syncthreads();
  mlp_layer(acc, xs, Ws, bs, r, cg);             // h2
  {
    float4* o4 = (float4*)(outA + (rowbase + r) * 64 + cg * 16);
#pragma unroll
    for (int q = 0; q < 4; ++q)
      o4[q] = make_float4(acc[q*4+0], acc[q*4+1], acc[q*4+2], acc[q*4+3]);
  }
  __syncthreads();
#pragma unroll
  for (int i = 0; i < 16; ++i) {
    xs[(cg * 16 + i) * 65 + r] = acc[i];
    Ws[tid + 256 * i] = wmm[tid + 256 * i];
  }
  if (tid < 64) bs[tid] = bmm[tid];
  __syncthreads();
  {   // flush AT (h2 transposed, feature-major)
    const size_t bb = rowbase >> 11;
    const int nbase = (int)(rowbase & 2047);
    const int c = tid >> 2, seg = tid & 3;
    float* oT = outAT + bb * 64 * N_NODES + (size_t)c * N_NODES + nbase + seg * 16;
#pragma unroll
    for (int q = 0; q < 4; ++q)
      ((float4*)oT)[q] = make_float4(xs[c*65+seg*16+q*4+0], xs[c*65+seg*16+q*4+1],
                                     xs[c*65+seg*16+q*4+2], xs[c*65+seg*16+q*4+3]);
  }
  mlp_layer(acc, xs, Ws, bs, r, cg);             // msg0
  {
    float4* o4 = (float4*)(outM + (rowbase + r) * 64 + cg * 16);
#pragma unroll
    for (int q = 0; q < 4; ++q)
      o4[q] = make_float4(acc[q*4+0], acc[q*4+1], acc[q*4+2], acc[q*4+3]);
  }
}

// Fused mp, 4-row/256-thread blocks (4096 blocks): the R15-proven structure
// (best measured: 540.5 us total). R19 adds ONLY a fused msg-out tail:
// when wm!=nullptr, each wave computes msg_next[row] = relu(bm + h2row @ wm)
// from hrL (wave-private row, written pre-barrier) and stores to outm --
// this replaces the standalone linrelu dispatch. outm=A is race-free in mp0:
// A rows are read exclusively by their owning block (hrow/hrL), and the
// msg write happens at the end of that same block.
template <bool FINAL>
__global__ __launch_bounds__(256, 4) void mp_kernel(
    const float* __restrict__ h, const float* __restrict__ hT,
    const float* __restrict__ msg,
    const float* __restrict__ wu, const float* __restrict__ bu,
    float* __restrict__ outp, float* __restrict__ outT,
    const float* __restrict__ wm, const float* __restrict__ bm,
    float* __restrict__ outm)
{
  const int tid = threadIdx.x;
  const int lane = tid & 63;
  const int w64 = tid >> 6;               // 4 waves <-> 4 rows
  const int bid = blockIdx.x;
  const int b = bid & 7;                  // round-robin blockIdx->XCD: 1 batch/XCD
  const int n0 = (bid >> 3) * ROWS;

  __shared__ unsigned Sbuf[ROWS * N_NODES];   // 32 KB ordered-uint S tile
  __shared__ unsigned hist[ROWS][256];        // 4 KB radix histograms
  __shared__ float    hrL[ROWS * 64];         // 1 KB epilogue row tile
  __shared__ unsigned LwMin[ROWS][ROWS], LwMax[ROWS][ROWS];
  __shared__ int   seli[ROWS][52];
  __shared__ float selv[ROWS][52];
  __shared__ int   eqlist[ROWS][56];

  const float* hb  = h  + (size_t)b * N_NODES * 64;
  const float* hTb = hT + (size_t)b * 64 * N_NODES;
  const float* colp = hTb + 4 * tid;      // group A: cols 4*tid..+3; B at +1024

  // prefetch ring depth 4 per group (issued before anything else)
  float4 pfA[4], pfB[4];
#pragma unroll
  for (int i = 0; i < 4; ++i) {
    pfA[i] = *(const float4*)(colp + (size_t)i * 2048);
    pfB[i] = *(const float4*)(colp + (size_t)i * 2048 + 1024);
  }

  if (!FINAL) hrL[tid] = hb[(size_t)n0 * 64 + tid];    // ROWS*64 == 256
  for (int i = tid; i < ROWS * 256; i += 256) (&hist[0][0])[i] = 0;

  // ---- FMA phase: acc2[r*4+q]: q=0,1 -> group A pairs; q=2,3 -> group B pairs
  v2f acc2[16];
#pragma unroll
  for (int i = 0; i < 16; ++i) { acc2[i][0] = 0.f; acc2[i][1] = 0.f; }

  const float* hrow = hb + (size_t)n0 * 64;            // block-uniform -> SGPR
  float4 a_cur[ROWS], a_nxt[ROWS];
#pragma unroll
  for (int r = 0; r < ROWS; ++r)
    a_cur[r] = *(const float4*)(hrow + r * 64);
  for (int k4 = 0; k4 < 16; ++k4) {
    if (k4 + 1 < 16) {                                 // prefetch next k4's rows
#pragma unroll
      for (int r = 0; r < ROWS; ++r)
        a_nxt[r] = *(const float4*)(hrow + r * 64 + (k4 + 1) * 4);
    }
#pragma unroll
    for (int kk = 0; kk < 4; ++kk) {
      const int k = k4 * 4 + kk;
      float4 cA = pfA[kk], cB = pfB[kk];               // ring: kk == k&3
      if (k + 4 < 64) {
        pfA[kk] = *(const float4*)(colp + (size_t)(k + 4) * 2048);
        pfB[kk] = *(const float4*)(colp + (size_t)(k + 4) * 2048 + 1024);
      }
      v2f cA0 = {cA.x, cA.y}, cA1 = {cA.z, cA.w};
      v2f cB0 = {cB.x, cB.y}, cB1 = {cB.z, cB.w};
#pragma unroll
      for (int r = 0; r < ROWS; ++r) {
        const float ar = ((const float*)&a_cur[r])[kk];
        v2f as = {ar, ar};
        acc2[r*4+0] = __builtin_elementwise_fma(as, cA0, acc2[r*4+0]);
        acc2[r*4+1] = __builtin_elementwise_fma(as, cA1, acc2[r*4+1]);
        acc2[r*4+2] = __builtin_elementwise_fma(as, cB0, acc2[r*4+2]);
        acc2[r*4+3] = __builtin_elementwise_fma(as, cB1, acc2[r*4+3]);
      }
    }
#pragma unroll
    for (int r = 0; r < ROWS; ++r) a_cur[r] = a_nxt[r];
  }

  // ---- convert, park in LDS, reg-based prefilter reductions
#pragma unroll
  for (int r = 0; r < ROWS; ++r) {
    uint4 wA, wB;
    wA.x = ford(acc2[r*4+0][0]); wA.y = ford(acc2[r*4+0][1]);
    wA.z = ford(acc2[r*4+1][0]); wA.w = ford(acc2[r*4+1][1]);
    wB.x = ford(acc2[r*4+2][0]); wB.y = ford(acc2[r*4+2][1]);
    wB.z = ford(acc2[r*4+3][0]); wB.w = ford(acc2[r*4+3][1]);
    *(uint4*)&Sbuf[r * N_NODES + 4 * tid] = wA;
    *(uint4*)&Sbuf[r * N_NODES + 1024 + 4 * tid] = wB;
    unsigned mA1 = wA.x > wA.y ? wA.x : wA.y, mA2 = wA.z > wA.w ? wA.z : wA.w;
    unsigned mB1 = wB.x > wB.y ? wB.x : wB.y, mB2 = wB.z > wB.w ? wB.z : wB.w;
    unsigned mA = mA1 > mA2 ? mA1 : mA2, mB = mB1 > mB2 ? mB1 : mB2;
    unsigned lm = mA > mB ? mA : mB;           // per-lane max of its 8 vals
    unsigned mn = lm, mx = lm;
#pragma unroll
    for (int off = 32; off >= 1; off >>= 1) {
      unsigned o1 = (unsigned)__shfl_xor((int)mn, off, 64);
      unsigned o2 = (unsigned)__shfl_xor((int)mx, off, 64);
      mn = mn < o1 ? mn : o1;                  // wave-min of lane maxes
      mx = mx > o2 ? mx : o2;                  // wave-max
    }
    if (lane == 0) { LwMin[w64][r] = mn; LwMax[w64][r] = mx; }
  }
  __syncthreads();                             // barrier 1: Sbuf/LwMM/hrL ready

  // ======== wave-private selection: wave w64 owns row rw ========
  const int rw = w64;
  const unsigned* Srow = &Sbuf[rw * N_NODES];
  unsigned Lv, Tv;
  {
    unsigned lmn = (lane < ROWS) ? LwMin[lane][rw] : 0u;
    unsigned lmx = (lane < ROWS) ? LwMax[lane][rw] : 0u;
#pragma unroll
    for (int off = 2; off >= 1; off >>= 1) {
      unsigned o1 = (unsigned)__shfl_xor((int)lmn, off, 4);
      unsigned o2 = (unsigned)__shfl_xor((int)lmx, off, 4);
      lmn = lmn > o1 ? lmn : o1;               // L = max over waves of wave-mins
      lmx = lmx > o2 ? lmx : o2;               // M = row max
    }
    Lv = (unsigned)__shfl((int)lmn, 0, 64);
    unsigned Mv = (unsigned)__shfl((int)lmx, 0, 64);

    if (Lv == Mv) {
      Tv = Mv;                                 // >=64 copies of the max
    } else {
      int sh = 24 - 8 * (__builtin_clz(Lv ^ Mv) >> 3);
      unsigned pv = (unsigned)(((unsigned long long)Lv) >> (sh + 8));
      unsigned Kc = KSEL;
      int mode = 0;                            // 0=HIST 1=PROBE 2=DONE
      unsigned* hrw = hist[rw];
      for (int it = 0; it < 5 && mode != 2; ++it) {
        // wave-uniform candidate range: prefix pv at bits [31 : sh+8]
        // <=> lo2 <= v <= hi  (two compares/value, hoist-proof)
        const int s2 = sh + 8;                 // 8..32
        const unsigned lo = (s2 >= 32) ? 0u : (pv << s2);
        const unsigned hi = (s2 >= 32) ? 0xFFFFFFFFu : (lo | ((1u << s2) - 1u));
        const unsigned lo2 = lo > Lv ? lo : Lv;
        if (mode == 0) {
#pragma unroll
          for (int i = 0; i < 8; ++i) {
            uint4 q = *(const uint4*)&Srow[i * 256 + 4 * lane];
            unsigned vv[4] = {q.x, q.y, q.z, q.w};
#pragma unroll
            for (int e = 0; e < 4; ++e) {
              unsigned v = vv[e];
              if (v >= lo2 && v <= hi)
                atomicAdd(&hrw[hidx1((v >> sh) & 255u)], 1u);
            }
          }
          uint4 q = *(const uint4*)&hrw[lane * 4];
          *(uint4*)&hrw[lane * 4] = make_uint4(0, 0, 0, 0);
          unsigned c0 = q.x, c1 = q.y, c2 = q.z, c3 = q.w;
          unsigned s0 = c0, s1 = c1, s2s = c2, s3 = c3;  // suffix over lanes
#pragma unroll
          for (int off = 1; off < 64; off <<= 1) {
            unsigned t0=__shfl_down((int)s0,off,64), t1=__shfl_down((int)s1,off,64);
            unsigned t2=__shfl_down((int)s2s,off,64), t3=__shfl_down((int)s3,off,64);
            if (lane + off < 64) { s0+=t0; s1+=t1; s2s+=t2; s3+=t3; }
          }
          unsigned T1=(unsigned)__shfl((int)s1,0,64);
          unsigned T2=(unsigned)__shfl((int)s2s,0,64);
          unsigned T3=(unsigned)__shfl((int)s3,0,64);
          unsigned cA4[4] = {c0, c1, c2, c3};
          unsigned AA[4] = {s0 - c0 + T1 + T2 + T3, s1 - c1 + T2 + T3,
                            s2s - c2 + T3,          s3 - c3};
          int fg = -1;
#pragma unroll
          for (int g = 0; g < 4; ++g)
            if (AA[g] < Kc && Kc <= AA[g] + cA4[g]) fg = g;
          unsigned long long mk = __ballot(fg >= 0);
          int src = __ffsll(mk) - 1;           // exactly one lane fires
          unsigned bin = 0, nKc = 0, cnt = 0;
          if (fg >= 0) {
            bin = (unsigned)(fg * 64 + lane);
            nKc = Kc - AA[fg];
            cnt = cA4[fg];
          }
          bin = (unsigned)__shfl((int)bin, src, 64);
          nKc = (unsigned)__shfl((int)nKc, src, 64);
          cnt = (unsigned)__shfl((int)cnt, src, 64);
          pv = (pv << 8) | bin;
          Kc = nKc;
          sh -= 8;
          if (sh < 0)        { Tv = pv; mode = 2; }
          else if (cnt == 1) mode = 1;
        } else {
          // PROBE: the unique candidate in [lo2,hi] is T
          unsigned found = 0; bool has = false;
#pragma unroll
          for (int i = 0; i < 8; ++i) {
            uint4 q = *(const uint4*)&Srow[i * 256 + 4 * lane];
            unsigned vv[4] = {q.x, q.y, q.z, q.w};
#pragma unroll
            for (int e = 0; e < 4; ++e) {
              unsigned v = vv[e];
              if (v >= lo2 && v <= hi) { found = v; has = true; }
            }
          }
          unsigned long long mk = __ballot(has);
          int src = __ffsll(mk) - 1;
          Tv = (unsigned)__shfl((int)found, src, 64);
          mode = 2;
        }
      }
    }
  }

  // ---- extraction: load row once (select state dead), counts + prefix scans
  unsigned vals[32];
  int cgt = 0, ceq = 0;
#pragma unroll
  for (int i = 0; i < 8; ++i) {
    uint4 q = *(const uint4*)&Srow[i * 256 + 4 * lane];
    vals[i*4+0] = q.x; vals[i*4+1] = q.y; vals[i*4+2] = q.z; vals[i*4+3] = q.w;
#pragma unroll
    for (int e = 0; e < 4; ++e) {
      cgt += (vals[i*4+e] > Tv);
      ceq += (vals[i*4+e] == Tv);
    }
  }
  int sg = cgt, se = ceq;
#pragma unroll
  for (int off = 1; off < 64; off <<= 1) {
    int t0 = __shfl_up(sg, off, 64), t1 = __shfl_up(se, off, 64);
    if (lane >= off) { sg += t0; se += t1; }
  }
  const int gW = __shfl(sg, 63, 64);           // total winners (> T), < 50
  const int eTot = __shfl(se, 63, 64);
  int gb = sg - cgt, eb = se - ceq;            // exclusive bases

  float* ob = FINAL ? (outp + ((size_t)b * N_NODES + n0 + rw) * N_NODES) : nullptr;
  if constexpr (FINAL) {
    // masked dense write fused with extraction; ties fixed up after resolve
#pragma unroll
    for (int i = 0; i < 8; ++i) {
      float4 w; float* wf = (float*)&w;
#pragma unroll
      for (int e = 0; e < 4; ++e) {
        unsigned v = vals[i*4+e];
        wf[e] = (v > Tv) ? funord(v) : 0.f;
        if (v == Tv) { if (eb < 56) eqlist[rw][eb] = i * 256 + 4 * lane + e; ++eb; }
      }
      *(float4*)(ob + i * 256 + 4 * lane) = w;
    }
  } else {
#pragma unroll
    for (int i = 0; i < 8; ++i) {
#pragma unroll
      for (int e = 0; e < 4; ++e) {
        unsigned v = vals[i*4+e];
        int m = i * 256 + 4 * lane + e;
        if (v > Tv) { seli[rw][gb] = m; selv[rw][gb] = funord(v); ++gb; }
        else if (v == Tv) { if (eb < 56) eqlist[rw][eb] = m; ++eb; }
      }
    }
  }
  const int eW = eTot < 56 ? eTot : 56;

  // ---- tie-resolve, wave-parallel: `need` smallest indices among equals
  const int needW = KSEL - gW;
  const float Tf = funord(Tv);
  {
    int myi = (lane < eW) ? eqlist[rw][lane] : 0x7FFFFFFF;
    for (int t = 0; t < needW; ++t) {
      int mn = myi;
#pragma unroll
      for (int off = 32; off >= 1; off >>= 1) {
        int o = __shfl_xor(mn, off, 64);
        mn = mn < o ? mn : o;
      }
      if (mn == 0x7FFFFFFF) break;
      if (myi == mn) {
        if (!FINAL) { seli[rw][gW + t] = mn; selv[rw][gW + t] = Tf; }
        else eqlist[rw][t] = mn;               // reuse as fixup list
        myi = 0x7FFFFFFF;
      }
    }
  }

  if constexpr (FINAL) {
    if (lane < needW) ob[eqlist[rw][lane]] = Tf;         // tie fixups
  } else {
    // aggregation into per-row Sbuf overlay (wave-private region; row is dead)
    // batched gather: groups of 10 independent L2 loads in flight
    float* aggbR = (float*)&Sbuf[rw * N_NODES + 1024];
    {
      const float* msgb = msg + (size_t)b * N_NODES * 64;
      float a0 = 0.f, a1 = 0.f;
#pragma unroll
      for (int i0 = 0; i0 < KSEL; i0 += 10) {
        int mi[10]; float vv[10], mv[10];
#pragma unroll
        for (int j = 0; j < 10; ++j) {
          mi[j] = seli[rw][i0 + j];            // wave-uniform LDS broadcast
          vv[j] = selv[rw][i0 + j];
        }
#pragma unroll
        for (int j = 0; j < 10; ++j)
          mv[j] = msgb[(size_t)mi[j] * 64 + lane];
#pragma unroll
        for (int j = 0; j < 10; ++j) {
          if (j & 1) a1 += vv[j] * mv[j];
          else       a0 += vv[j] * mv[j];
        }
      }
      aggbR[lane] = a0 + a1;
    }
    // update MLP: h2[rw][lane]; dual chains break the serial FMA dependency
    float s0 = bu[lane], s1 = 0.f;
#pragma unroll 8
    for (int jj = 0; jj < 64; jj += 2) {
      s0 += hrL[rw * 64 + jj]     * wu[jj * 64 + lane];
      s1 += hrL[rw * 64 + jj + 1] * wu[(jj + 1) * 64 + lane];
    }
#pragma unroll 8
    for (int jj = 0; jj < 64; jj += 2) {
      s0 += aggbR[jj]     * wu[(64 + jj) * 64 + lane];
      s1 += aggbR[jj + 1] * wu[(64 + jj + 1) * 64 + lane];
    }
    float s = fmaxf(s0 + s1, 0.f);
    outp[((size_t)b * N_NODES + n0 + rw) * 64 + lane] = s;
    hrL[rw * 64 + lane] = s;                   // stash row for fused msg (hrL dead)
    __syncthreads();                           // all waves done with Sbuf
    float* otF = (float*)Sbuf;                 // transpose staging overlay
    otF[lane * 9 + rw] = s;                    // stride 9: conflict-free
    __syncthreads();
    {                                          // flush h2T: 64 feats x 4 rows
      int f = tid >> 2, rr = tid & 3;
      outT[(size_t)b * 64 * N_NODES + (size_t)f * N_NODES + n0 + rr] = otF[f * 9 + rr];
    }
    if (wm) {                                  // fused msg_next = relu(bm + h@wm)
      float t0 = bm[lane], t1 = 0.f;
#pragma unroll 8
      for (int jj = 0; jj < 64; jj += 2) {
        t0 += hrL[rw * 64 + jj]     * wm[jj * 64 + lane];
        t1 += hrL[rw * 64 + jj + 1] * wm[(jj + 1) * 64 + lane];
      }
      outm[((size_t)b * N_NODES + n0 + rw) * 64 + lane] = fmaxf(t0 + t1, 0.f);
    }
  }
}

extern "C" void kernel_launch(void* const* d_in, const int* in_sizes, int n_in,
                              void* d_out, int out_size, void* d_ws, size_t ws_size,
                              hipStream_t stream)
{
  (void)in_sizes; (void)n_in; (void)out_size; (void)ws_size;
  const float* x   = (const float*)d_in[0];
  const float* ew0 = (const float*)d_in[1];
  const float* eb0 = (const float*)d_in[2];
  const float* ew1 = (const float*)d_in[3];
  const float* eb1 = (const float*)d_in[4];
  const float* w0m = (const float*)d_in[5];
  const float* b0m = (const float*)d_in[6];
  const float* w0u = (const float*)d_in[7];
  const float* b0u = (const float*)d_in[8];
  const float* w1m = (const float*)d_in[9];
  const float* b1m = (const float*)d_in[10];
  const float* w1u = (const float*)d_in[11];
  const float* b1u = (const float*)d_in[12];
  float* out = (float*)d_out;
  float* ws = (float*)d_ws;

  const size_t BUF = (size_t)8 * N_NODES * 64;  // 4 MB each, 20 MB total ws
  float* A   = ws;
  float* AT  = ws + 1 * BUF;
  float* Bf  = ws + 2 * BUF;
  float* BfT = ws + 3 * BUF;
  float* C   = ws + 4 * BUF;

  const int NBLK = 8 * (N_NODES / ROWS);        // 4096

  // fused embedding (2 layers) + msg0 -> A(h2), AT(h2T), C(msg0)
  emb3_kernel<<<256, 256, 0, stream>>>(x, ew0, eb0, ew1, eb1, w0m, b0m, A, AT, C);

  // MP layer 0: reads A/AT/C; writes Bf(h3), BfT(h3T); fused msg1 -> A
  // (A rows are block-private reads in mp0, written last by the same block)
  mp_kernel<false><<<NBLK, 256, 0, stream>>>(A, AT, C, w0u, b0u, Bf, BfT,
                                             w1m, b1m, A);

  // MP layer 1: reads Bf/BfT + msg1(A); writes C(h4), AT(h4T); no fused msg
  mp_kernel<false><<<NBLK, 256, 0, stream>>>(Bf, BfT, A, w1u, b1u, C, AT,
                                             nullptr, nullptr, nullptr);

  // final dense top-k adjacency from C/AT
  mp_kernel<true><<<NBLK, 256, 0, stream>>>(C, AT, nullptr, nullptr, nullptr,
                                            out, nullptr,
                                            nullptr, nullptr, nullptr);
}

// Round 6
// 522.893 us; speedup vs baseline: 2.9372x; 1.0160x over previous
//
#include <hip/hip_runtime.h>

#define N_NODES 2048
#define KSEL 50
#define ROWS 4

typedef float v2f __attribute__((ext_vector_type(2)));

// ---- order-preserving fp32 <-> uint map (monotone: bigger float => bigger uint)
__device__ __forceinline__ unsigned ford(float f) {
  unsigned b = __float_as_uint(f);
  return b ^ ((b & 0x80000000u) ? 0xFFFFFFFFu : 0x80000000u);
}
__device__ __forceinline__ float funord(unsigned u) {
  unsigned b = (u & 0x80000000u) ? (u ^ 0x80000000u) : ~u;
  return __uint_as_float(b);
}

// 1-sub-counter hist layout: bin b -> word ((b&63)<<2)|(b>>6).
// Scan: lane reads uint4 at [lane*4] = bins {g*64+lane}, g=0..3 (components).
__device__ __forceinline__ int hidx1(unsigned b) {
  return (int)(((b & 63u) << 2) | (b >> 6));
}

// shared single-layer MLP tile: acc[16] = relu(bias + xs^T W), xs transposed layout
__device__ __forceinline__ void mlp_layer(float acc[16], const float* xs,
                                          const float* Ws, const float* bs,
                                          int r, int cg) {
  const float4* Ws4 = (const float4*)Ws;
#pragma unroll
  for (int i = 0; i < 16; ++i) acc[i] = bs[cg * 16 + i];
#pragma unroll 8
  for (int k = 0; k < 64; ++k) {
    float xv = xs[k * 65 + r];
    float4 w0 = Ws4[k * 16 + cg * 4 + 0];
    float4 w1 = Ws4[k * 16 + cg * 4 + 1];
    float4 w2 = Ws4[k * 16 + cg * 4 + 2];
    float4 w3 = Ws4[k * 16 + cg * 4 + 3];
    acc[0]  += xv * w0.x; acc[1]  += xv * w0.y; acc[2]  += xv * w0.z; acc[3]  += xv * w0.w;
    acc[4]  += xv * w1.x; acc[5]  += xv * w1.y; acc[6]  += xv * w1.z; acc[7]  += xv * w1.w;
    acc[8]  += xv * w2.x; acc[9]  += xv * w2.y; acc[10] += xv * w2.z; acc[11] += xv * w2.w;
    acc[12] += xv * w3.x; acc[13] += xv * w3.y; acc[14] += xv * w3.z; acc[15] += xv * w3.w;
  }
#pragma unroll
  for (int i = 0; i < 16; ++i) acc[i] = fmaxf(acc[i], 0.f);
}

// Fused embedding: h1=relu(x@w0+b0); h2=relu(h1@w1+b1) -> A, AT; msg0=relu(h2@wm+bm) -> M
__global__ __launch_bounds__(256) void emb3_kernel(
    const float* __restrict__ x,
    const float* __restrict__ ew0, const float* __restrict__ eb0,
    const float* __restrict__ ew1, const float* __restrict__ eb1,
    const float* __restrict__ wmm, const float* __restrict__ bmm,
    float* __restrict__ outA, float* __restrict__ outAT, float* __restrict__ outM)
{
  const int tid = threadIdx.x;
  const int r = tid & 63, cg = tid >> 6;
  const size_t rowbase = (size_t)blockIdx.x * 64;
  __shared__ float xs[64 * 65];
  __shared__ float Ws[64 * 64];
  __shared__ float bs[64];
  float acc[16];

#pragma unroll
  for (int i = 0; i < 16; ++i) {
    int idx = tid + 256 * i;
    xs[(idx & 63) * 65 + (idx >> 6)] = x[rowbase * 64 + idx];
    Ws[idx] = ew0[idx];
  }
  if (tid < 64) bs[tid] = eb0[tid];
  __syncthreads();
  mlp_layer(acc, xs, Ws, bs, r, cg);             // h1
  __syncthreads();
#pragma unroll
  for (int i = 0; i < 16; ++i) {
    xs[(cg * 16 + i) * 65 + r] = acc[i];
    Ws[tid + 256 * i] = ew1[tid + 256 * i];
  }
  if (tid < 64) bs[tid] = eb1[tid];
  __syncthreads();
  mlp_layer(acc, xs, Ws, bs, r, cg);             // h2
  {
    float4* o4 = (float4*)(outA + (rowbase + r) * 64 + cg * 16);
#pragma unroll
    for (int q = 0; q < 4; ++q)
      o4[q] = make_float4(acc[q*4+0], acc[q*4+1], acc[q*4+2], acc[q*4+3]);
  }
  __syncthreads();
#pragma unroll
  for (int i = 0; i < 16; ++i) {
    xs[(cg * 16 + i) * 65 + r] = acc[i];
    Ws[tid + 256 * i] = wmm[tid + 256 * i];
  }
  if (tid < 64) bs[tid] = bmm[tid];
  __syncthreads();
  {   // flush AT (h2 transposed, feature-major)
    const size_t bb = rowbase >> 11;
    const int nbase = (int)(rowbase & 2047);
    const int c = tid >> 2, seg = tid & 3;
    float* oT = outAT + bb * 64 * N_NODES + (size_t)c * N_NODES + nbase + seg * 16;
#pragma unroll
    for (int q = 0; q < 4; ++q)
      ((float4*)oT)[q] = make_float4(xs[c*65+seg*16+q*4+0], xs[c*65+seg*16+q*4+1],
                                     xs[c*65+seg*16+q*4+2], xs[c*65+seg*16+q*4+3]);
  }
  mlp_layer(acc, xs, Ws, bs, r, cg);             // msg0
  {
    float4* o4 = (float4*)(outM + (rowbase + r) * 64 + cg * 16);
#pragma unroll
    for (int q = 0; q < 4; ++q)
      o4[q] = make_float4(acc[q*4+0], acc[q*4+1], acc[q*4+2], acc[q*4+3]);
  }
}

// Fused mp, 4-row/256-thread blocks (4096 blocks): R15-proven structure +
// R19 fused msg tail. R20: seli/selv/eqlist OVERLAY into hist[rw] (hist is
// dead once the select releases it; both regions are strictly wave-private
// per row) -> LDS 40576 -> 38016 B, dropping below the 4-blocks/CU LDS
// boundary (4 x ~38.9KB = 155.6KB < 160KB; R19's 4 x 40960 = exactly 163840
// only fit 3). Goal: occupancy 38.7% -> ~50%, +1 block of latency-hiding.
template <bool FINAL>
__global__ __launch_bounds__(256, 4) void mp_kernel(
    const float* __restrict__ h, const float* __restrict__ hT,
    const float* __restrict__ msg,
    const float* __restrict__ wu, const float* __restrict__ bu,
    float* __restrict__ outp, float* __restrict__ outT,
    const float* __restrict__ wm, const float* __restrict__ bm,
    float* __restrict__ outm)
{
  const int tid = threadIdx.x;
  const int lane = tid & 63;
  const int w64 = tid >> 6;               // 4 waves <-> 4 rows
  const int bid = blockIdx.x;
  const int b = bid & 7;                  // round-robin blockIdx->XCD: 1 batch/XCD
  const int n0 = (bid >> 3) * ROWS;

  __shared__ unsigned Sbuf[ROWS * N_NODES];   // 32 KB ordered-uint S tile
  __shared__ unsigned hist[ROWS][256];        // 4 KB radix hists; post-select overlay:
                                              //   [0..51]=seli [64..115]=selv [128..183]=eqlist
  __shared__ float    hrL[ROWS * 64];         // 1 KB epilogue row tile
  __shared__ unsigned LwMin[ROWS][ROWS], LwMax[ROWS][ROWS];

  const float* hb  = h  + (size_t)b * N_NODES * 64;
  const float* hTb = hT + (size_t)b * 64 * N_NODES;
  const float* colp = hTb + 4 * tid;      // group A: cols 4*tid..+3; B at +1024

  // prefetch ring depth 4 per group (issued before anything else)
  float4 pfA[4], pfB[4];
#pragma unroll
  for (int i = 0; i < 4; ++i) {
    pfA[i] = *(const float4*)(colp + (size_t)i * 2048);
    pfB[i] = *(const float4*)(colp + (size_t)i * 2048 + 1024);
  }

  if (!FINAL) hrL[tid] = hb[(size_t)n0 * 64 + tid];    // ROWS*64 == 256
  for (int i = tid; i < ROWS * 256; i += 256) (&hist[0][0])[i] = 0;

  // ---- FMA phase: acc2[r*4+q]: q=0,1 -> group A pairs; q=2,3 -> group B pairs
  v2f acc2[16];
#pragma unroll
  for (int i = 0; i < 16; ++i) { acc2[i][0] = 0.f; acc2[i][1] = 0.f; }

  const float* hrow = hb + (size_t)n0 * 64;            // block-uniform -> SGPR
  float4 a_cur[ROWS], a_nxt[ROWS];
#pragma unroll
  for (int r = 0; r < ROWS; ++r)
    a_cur[r] = *(const float4*)(hrow + r * 64);
  for (int k4 = 0; k4 < 16; ++k4) {
    if (k4 + 1 < 16) {                                 // prefetch next k4's rows
#pragma unroll
      for (int r = 0; r < ROWS; ++r)
        a_nxt[r] = *(const float4*)(hrow + r * 64 + (k4 + 1) * 4);
    }
#pragma unroll
    for (int kk = 0; kk < 4; ++kk) {
      const int k = k4 * 4 + kk;
      float4 cA = pfA[kk], cB = pfB[kk];               // ring: kk == k&3
      if (k + 4 < 64) {
        pfA[kk] = *(const float4*)(colp + (size_t)(k + 4) * 2048);
        pfB[kk] = *(const float4*)(colp + (size_t)(k + 4) * 2048 + 1024);
      }
      v2f cA0 = {cA.x, cA.y}, cA1 = {cA.z, cA.w};
      v2f cB0 = {cB.x, cB.y}, cB1 = {cB.z, cB.w};
#pragma unroll
      for (int r = 0; r < ROWS; ++r) {
        const float ar = ((const float*)&a_cur[r])[kk];
        v2f as = {ar, ar};
        acc2[r*4+0] = __builtin_elementwise_fma(as, cA0, acc2[r*4+0]);
        acc2[r*4+1] = __builtin_elementwise_fma(as, cA1, acc2[r*4+1]);
        acc2[r*4+2] = __builtin_elementwise_fma(as, cB0, acc2[r*4+2]);
        acc2[r*4+3] = __builtin_elementwise_fma(as, cB1, acc2[r*4+3]);
      }
    }
#pragma unroll
    for (int r = 0; r < ROWS; ++r) a_cur[r] = a_nxt[r];
  }

  // ---- convert, park in LDS, reg-based prefilter reductions
#pragma unroll
  for (int r = 0; r < ROWS; ++r) {
    uint4 wA, wB;
    wA.x = ford(acc2[r*4+0][0]); wA.y = ford(acc2[r*4+0][1]);
    wA.z = ford(acc2[r*4+1][0]); wA.w = ford(acc2[r*4+1][1]);
    wB.x = ford(acc2[r*4+2][0]); wB.y = ford(acc2[r*4+2][1]);
    wB.z = ford(acc2[r*4+3][0]); wB.w = ford(acc2[r*4+3][1]);
    *(uint4*)&Sbuf[r * N_NODES + 4 * tid] = wA;
    *(uint4*)&Sbuf[r * N_NODES + 1024 + 4 * tid] = wB;
    unsigned mA1 = wA.x > wA.y ? wA.x : wA.y, mA2 = wA.z > wA.w ? wA.z : wA.w;
    unsigned mB1 = wB.x > wB.y ? wB.x : wB.y, mB2 = wB.z > wB.w ? wB.z : wB.w;
    unsigned mA = mA1 > mA2 ? mA1 : mA2, mB = mB1 > mB2 ? mB1 : mB2;
    unsigned lm = mA > mB ? mA : mB;           // per-lane max of its 8 vals
    unsigned mn = lm, mx = lm;
#pragma unroll
    for (int off = 32; off >= 1; off >>= 1) {
      unsigned o1 = (unsigned)__shfl_xor((int)mn, off, 64);
      unsigned o2 = (unsigned)__shfl_xor((int)mx, off, 64);
      mn = mn < o1 ? mn : o1;                  // wave-min of lane maxes
      mx = mx > o2 ? mx : o2;                  // wave-max
    }
    if (lane == 0) { LwMin[w64][r] = mn; LwMax[w64][r] = mx; }
  }
  __syncthreads();                             // barrier 1: Sbuf/LwMM/hrL ready

  // ======== wave-private selection: wave w64 owns row rw ========
  const int rw = w64;
  const unsigned* Srow = &Sbuf[rw * N_NODES];
  int*   seliR = (int*)  &hist[rw][0];         // post-select overlays (wave-private)
  float* selvR = (float*)&hist[rw][64];
  int*   eqR   = (int*)  &hist[rw][128];
  unsigned Lv, Tv;
  {
    unsigned lmn = (lane < ROWS) ? LwMin[lane][rw] : 0u;
    unsigned lmx = (lane < ROWS) ? LwMax[lane][rw] : 0u;
#pragma unroll
    for (int off = 2; off >= 1; off >>= 1) {
      unsigned o1 = (unsigned)__shfl_xor((int)lmn, off, 4);
      unsigned o2 = (unsigned)__shfl_xor((int)lmx, off, 4);
      lmn = lmn > o1 ? lmn : o1;               // L = max over waves of wave-mins
      lmx = lmx > o2 ? lmx : o2;               // M = row max
    }
    Lv = (unsigned)__shfl((int)lmn, 0, 64);
    unsigned Mv = (unsigned)__shfl((int)lmx, 0, 64);

    if (Lv == Mv) {
      Tv = Mv;                                 // >=64 copies of the max
    } else {
      int sh = 24 - 8 * (__builtin_clz(Lv ^ Mv) >> 3);
      unsigned pv = (unsigned)(((unsigned long long)Lv) >> (sh + 8));
      unsigned Kc = KSEL;
      int mode = 0;                            // 0=HIST 1=PROBE 2=DONE
      unsigned* hrw = hist[rw];
      for (int it = 0; it < 5 && mode != 2; ++it) {
        // wave-uniform candidate range: prefix pv at bits [31 : sh+8]
        // <=> lo2 <= v <= hi  (two compares/value, hoist-proof)
        const int s2 = sh + 8;                 // 8..32
        const unsigned lo = (s2 >= 32) ? 0u : (pv << s2);
        const unsigned hi = (s2 >= 32) ? 0xFFFFFFFFu : (lo | ((1u << s2) - 1u));
        const unsigned lo2 = lo > Lv ? lo : Lv;
        if (mode == 0) {
#pragma unroll
          for (int i = 0; i < 8; ++i) {
            uint4 q = *(const uint4*)&Srow[i * 256 + 4 * lane];
            unsigned vv[4] = {q.x, q.y, q.z, q.w};
#pragma unroll
            for (int e = 0; e < 4; ++e) {
              unsigned v = vv[e];
              if (v >= lo2 && v <= hi)
                atomicAdd(&hrw[hidx1((v >> sh) & 255u)], 1u);
            }
          }
          uint4 q = *(const uint4*)&hrw[lane * 4];
          *(uint4*)&hrw[lane * 4] = make_uint4(0, 0, 0, 0);
          unsigned c0 = q.x, c1 = q.y, c2 = q.z, c3 = q.w;
          unsigned s0 = c0, s1 = c1, s2s = c2, s3 = c3;  // suffix over lanes
#pragma unroll
          for (int off = 1; off < 64; off <<= 1) {
            unsigned t0=__shfl_down((int)s0,off,64), t1=__shfl_down((int)s1,off,64);
            unsigned t2=__shfl_down((int)s2s,off,64), t3=__shfl_down((int)s3,off,64);
            if (lane + off < 64) { s0+=t0; s1+=t1; s2s+=t2; s3+=t3; }
          }
          unsigned T1=(unsigned)__shfl((int)s1,0,64);
          unsigned T2=(unsigned)__shfl((int)s2s,0,64);
          unsigned T3=(unsigned)__shfl((int)s3,0,64);
          unsigned cA4[4] = {c0, c1, c2, c3};
          unsigned AA[4] = {s0 - c0 + T1 + T2 + T3, s1 - c1 + T2 + T3,
                            s2s - c2 + T3,          s3 - c3};
          int fg = -1;
#pragma unroll
          for (int g = 0; g < 4; ++g)
            if (AA[g] < Kc && Kc <= AA[g] + cA4[g]) fg = g;
          unsigned long long mk = __ballot(fg >= 0);
          int src = __ffsll(mk) - 1;           // exactly one lane fires
          unsigned bin = 0, nKc = 0, cnt = 0;
          if (fg >= 0) {
            bin = (unsigned)(fg * 64 + lane);
            nKc = Kc - AA[fg];
            cnt = cA4[fg];
          }
          bin = (unsigned)__shfl((int)bin, src, 64);
          nKc = (unsigned)__shfl((int)nKc, src, 64);
          cnt = (unsigned)__shfl((int)cnt, src, 64);
          pv = (pv << 8) | bin;
          Kc = nKc;
          sh -= 8;
          if (sh < 0)        { Tv = pv; mode = 2; }
          else if (cnt == 1) mode = 1;
        } else {
          // PROBE: the unique candidate in [lo2,hi] is T
          unsigned found = 0; bool has = false;
#pragma unroll
          for (int i = 0; i < 8; ++i) {
            uint4 q = *(const uint4*)&Srow[i * 256 + 4 * lane];
            unsigned vv[4] = {q.x, q.y, q.z, q.w};
#pragma unroll
            for (int e = 0; e < 4; ++e) {
              unsigned v = vv[e];
              if (v >= lo2 && v <= hi) { found = v; has = true; }
            }
          }
          unsigned long long mk = __ballot(has);
          int src = __ffsll(mk) - 1;
          Tv = (unsigned)__shfl((int)found, src, 64);
          mode = 2;
        }
      }
    }
  }

  // ---- extraction: load row once (select state dead), counts + prefix scans
  unsigned vals[32];
  int cgt = 0, ceq = 0;
#pragma unroll
  for (int i = 0; i < 8; ++i) {
    uint4 q = *(const uint4*)&Srow[i * 256 + 4 * lane];
    vals[i*4+0] = q.x; vals[i*4+1] = q.y; vals[i*4+2] = q.z; vals[i*4+3] = q.w;
#pragma unroll
    for (int e = 0; e < 4; ++e) {
      cgt += (vals[i*4+e] > Tv);
      ceq += (vals[i*4+e] == Tv);
    }
  }
  int sg = cgt, se = ceq;
#pragma unroll
  for (int off = 1; off < 64; off <<= 1) {
    int t0 = __shfl_up(sg, off, 64), t1 = __shfl_up(se, off, 64);
    if (lane >= off) { sg += t0; se += t1; }
  }
  const int gW = __shfl(sg, 63, 64);           // total winners (> T), < 50
  const int eTot = __shfl(se, 63, 64);
  int gb = sg - cgt, eb = se - ceq;            // exclusive bases

  float* ob = FINAL ? (outp + ((size_t)b * N_NODES + n0 + rw) * N_NODES) : nullptr;
  if constexpr (FINAL) {
    // masked dense write fused with extraction; ties fixed up after resolve
#pragma unroll
    for (int i = 0; i < 8; ++i) {
      float4 w; float* wf = (float*)&w;
#pragma unroll
      for (int e = 0; e < 4; ++e) {
        unsigned v = vals[i*4+e];
        wf[e] = (v > Tv) ? funord(v) : 0.f;
        if (v == Tv) { if (eb < 56) eqR[eb] = i * 256 + 4 * lane + e; ++eb; }
      }
      *(float4*)(ob + i * 256 + 4 * lane) = w;
    }
  } else {
#pragma unroll
    for (int i = 0; i < 8; ++i) {
#pragma unroll
      for (int e = 0; e < 4; ++e) {
        unsigned v = vals[i*4+e];
        int m = i * 256 + 4 * lane + e;
        if (v > Tv) { seliR[gb] = m; selvR[gb] = funord(v); ++gb; }
        else if (v == Tv) { if (eb < 56) eqR[eb] = m; ++eb; }
      }
    }
  }
  const int eW = eTot < 56 ? eTot : 56;

  // ---- tie-resolve, wave-parallel: `need` smallest indices among equals
  const int needW = KSEL - gW;
  const float Tf = funord(Tv);
  {
    int myi = (lane < eW) ? eqR[lane] : 0x7FFFFFFF;
    for (int t = 0; t < needW; ++t) {
      int mn = myi;
#pragma unroll
      for (int off = 32; off >= 1; off >>= 1) {
        int o = __shfl_xor(mn, off, 64);
        mn = mn < o ? mn : o;
      }
      if (mn == 0x7FFFFFFF) break;
      if (myi == mn) {
        if (!FINAL) { seliR[gW + t] = mn; selvR[gW + t] = Tf; }
        else eqR[t] = mn;                      // reuse as fixup list
        myi = 0x7FFFFFFF;
      }
    }
  }

  if constexpr (FINAL) {
    if (lane < needW) ob[eqR[lane]] = Tf;      // tie fixups
  } else {
    // aggregation into per-row Sbuf overlay (wave-private region; row is dead)
    // batched gather: groups of 10 independent L2 loads in flight
    float* aggbR = (float*)&Sbuf[rw * N_NODES + 1024];
    {
      const float* msgb = msg + (size_t)b * N_NODES * 64;
      float a0 = 0.f, a1 = 0.f;
#pragma unroll
      for (int i0 = 0; i0 < KSEL; i0 += 10) {
        int mi[10]; float vv[10], mv[10];
#pragma unroll
        for (int j = 0; j < 10; ++j) {
          mi[j] = seliR[i0 + j];               // wave-uniform LDS broadcast
          vv[j] = selvR[i0 + j];
        }
#pragma unroll
        for (int j = 0; j < 10; ++j)
          mv[j] = msgb[(size_t)mi[j] * 64 + lane];
#pragma unroll
        for (int j = 0; j < 10; ++j) {
          if (j & 1) a1 += vv[j] * mv[j];
          else       a0 += vv[j] * mv[j];
        }
      }
      aggbR[lane] = a0 + a1;
    }
    // update MLP: h2[rw][lane]; dual chains break the serial FMA dependency
    float s0 = bu[lane], s1 = 0.f;
#pragma unroll 8
    for (int jj = 0; jj < 64; jj += 2) {
      s0 += hrL[rw * 64 + jj]     * wu[jj * 64 + lane];
      s1 += hrL[rw * 64 + jj + 1] * wu[(jj + 1) * 64 + lane];
    }
#pragma unroll 8
    for (int jj = 0; jj < 64; jj += 2) {
      s0 += aggbR[jj]     * wu[(64 + jj) * 64 + lane];
      s1 += aggbR[jj + 1] * wu[(64 + jj + 1) * 64 + lane];
    }
    float s = fmaxf(s0 + s1, 0.f);
    outp[((size_t)b * N_NODES + n0 + rw) * 64 + lane] = s;
    hrL[rw * 64 + lane] = s;                   // stash row for fused msg (hrL dead)
    __syncthreads();                           // all waves done with Sbuf
    float* otF = (float*)Sbuf;                 // transpose staging overlay
    otF[lane * 9 + rw] = s;                    // stride 9: conflict-free
    __syncthreads();
    {                                          // flush h2T: 64 feats x 4 rows
      int f = tid >> 2, rr = tid & 3;
      outT[(size_t)b * 64 * N_NODES + (size_t)f * N_NODES + n0 + rr] = otF[f * 9 + rr];
    }
    if (wm) {                                  // fused msg_next = relu(bm + h@wm)
      float t0 = bm[lane], t1 = 0.f;
#pragma unroll 8
      for (int jj = 0; jj < 64; jj += 2) {
        t0 += hrL[rw * 64 + jj]     * wm[jj * 64 + lane];
        t1 += hrL[rw * 64 + jj + 1] * wm[(jj + 1) * 64 + lane];
      }
      outm[((size_t)b * N_NODES + n0 + rw) * 64 + lane] = fmaxf(t0 + t1, 0.f);
    }
  }
}

extern "C" void kernel_launch(void* const* d_in, const int* in_sizes, int n_in,
                              void* d_out, int out_size, void* d_ws, size_t ws_size,
                              hipStream_t stream)
{
  (void)in_sizes; (void)n_in; (void)out_size; (void)ws_size;
  const float* x   = (const float*)d_in[0];
  const float* ew0 = (const float*)d_in[1];
  const float* eb0 = (const float*)d_in[2];
  const float* ew1 = (const float*)d_in[3];
  const float* eb1 = (const float*)d_in[4];
  const float* w0m = (const float*)d_in[5];
  const float* b0m = (const float*)d_in[6];
  const float* w0u = (const float*)d_in[7];
  const float* b0u = (const float*)d_in[8];
  const float* w1m = (const float*)d_in[9];
  const float* b1m = (const float*)d_in[10];
  const float* w1u = (const float*)d_in[11];
  const float* b1u = (const float*)d_in[12];
  float* out = (float*)d_out;
  float* ws = (float*)d_ws;

  const size_t BUF = (size_t)8 * N_NODES * 64;  // 4 MB each, 20 MB total ws
  float* A   = ws;
  float* AT  = ws + 1 * BUF;
  float* Bf  = ws + 2 * BUF;
  float* BfT = ws + 3 * BUF;
  float* C   = ws + 4 * BUF;

  const int NBLK = 8 * (N_NODES / ROWS);        // 4096

  // fused embedding (2 layers) + msg0 -> A(h2), AT(h2T), C(msg0)
  emb3_kernel<<<256, 256, 0, stream>>>(x, ew0, eb0, ew1, eb1, w0m, b0m, A, AT, C);

  // MP layer 0: reads A/AT/C; writes Bf(h3), BfT(h3T); fused msg1 -> A
  // (A rows are block-private reads in mp0, written last by the same block)
  mp_kernel<false><<<NBLK, 256, 0, stream>>>(A, AT, C, w0u, b0u, Bf, BfT,
                                             w1m, b1m, A);

  // MP layer 1: reads Bf/BfT + msg1(A); writes C(h4), AT(h4T); no fused msg
  mp_kernel<false><<<NBLK, 256, 0, stream>>>(Bf, BfT, A, w1u, b1u, C, AT,
                                             nullptr, nullptr, nullptr);

  // final dense top-k adjacency from C/AT
  mp_kernel<true><<<NBLK, 256, 0, stream>>>(C, AT, nullptr, nullptr, nullptr,
                                            out, nullptr,
                                            nullptr, nullptr, nullptr);
}